// Round 12
// baseline (392.037 us; speedup 1.0000x reference)
//
#include <hip/hip_runtime.h>
#include <hip/hip_fp16.h>
#include <hip/hip_cooperative_groups.h>
#include <math.h>
#include <stdint.h>

namespace cg = cooperative_groups;

#define D 128
#define BLK 256
typedef __attribute__((ext_vector_type(8))) _Float16 f16x8;
typedef __attribute__((ext_vector_type(4))) float f32x4;
typedef unsigned short ushort_t;

__device__ inline unsigned pack_f16(float a, float b) {
    __half2 h = __floats2half2_rn(a, b);
    return __builtin_bit_cast(unsigned, h);
}
__device__ inline ushort_t f16_of(float f) {
    __half h = __float2half_rn(f);
    return __builtin_bit_cast(ushort_t, h);
}
__device__ inline __half2 hmax2(__half2 a, __half2 b) {
    unsigned ua = __builtin_bit_cast(unsigned, a);
    unsigned ub = __builtin_bit_cast(unsigned, b);
    unsigned r;
    asm("v_pk_max_f16 %0, %1, %2" : "=v"(r) : "v"(ua), "v"(ub));
    return __builtin_bit_cast(__half2, r);
}

struct __align__(16) H8 { __half2 h[4]; };

// ---- LDS staging helpers (XOR-swizzled layout, 256B rows) ----
__device__ inline void stage_w(ushort_t* sW, const ushort_t* Wt, int t) {
    const uint4* src = (const uint4*)Wt;
    for (int s = t; s < 2048; s += BLK) {
        const int col = s >> 4;
        const int off = (s & 15) * 16;
        *(uint4*)((char*)sW + col * 256 + (off ^ ((col & 7) << 4))) = src[s];
    }
}
__device__ inline void stage_x(ushort_t* sX, const float* X, const int* rowidx,
                               int r0, int M, int t) {
    const int row = t >> 2, q = t & 3;
    const int gr = r0 + row;
    if (gr < M) {
        const int src = rowidx ? rowidx[gr] : gr;
        const float* xp = X + (size_t)src * D + q * 32;
        #pragma unroll
        for (int s = 0; s < 4; ++s) {
            const float4 v0 = *(const float4*)(xp + s * 8);
            const float4 v1 = *(const float4*)(xp + s * 8 + 4);
            uint4 pk;
            pk.x = pack_f16(v0.x, v0.y); pk.y = pack_f16(v0.z, v0.w);
            pk.z = pack_f16(v1.x, v1.y); pk.w = pack_f16(v1.z, v1.w);
            const int off = q * 64 + s * 16;
            *(uint4*)((char*)sX + row * 256 + (off ^ ((row & 7) << 4))) = pk;
        }
    }
}

// dual-weight 64-row tile: Y[gr][0:128]=X@(sWA), Y[gr][128:256]=X@(sWB), fp16 out
__device__ inline void dual_tile(const float* X, int r0, int M, ushort_t* Y,
                                 ushort_t* sWA, ushort_t* sWB, ushort_t* sX, int t) {
    const int wave = t >> 6, lane = t & 63;
    const int l15 = lane & 15, lg = lane >> 4;
    stage_x(sX, X, nullptr, r0, M, t);
    __syncthreads();
    f32x4 accA[8], accB[8];
    #pragma unroll
    for (int ct = 0; ct < 8; ++ct) {
        accA[ct] = (f32x4){0.f, 0.f, 0.f, 0.f};
        accB[ct] = (f32x4){0.f, 0.f, 0.f, 0.f};
    }
    #pragma unroll
    for (int kc = 0; kc < 4; ++kc) {
        const int koff = kc * 64 + lg * 16;
        const int arow = wave * 16 + l15;
        const f16x8 afrag = *(const f16x8*)((char*)sX + arow * 256 + (koff ^ ((arow & 7) << 4)));
        #pragma unroll
        for (int ct = 0; ct < 8; ++ct) {
            const int col = ct * 16 + l15;
            const int sw = koff ^ ((col & 7) << 4);
            const f16x8 bfA = *(const f16x8*)((char*)sWA + col * 256 + sw);
            const f16x8 bfB = *(const f16x8*)((char*)sWB + col * 256 + sw);
            accA[ct] = __builtin_amdgcn_mfma_f32_16x16x32_f16(afrag, bfA, accA[ct], 0, 0, 0);
            accB[ct] = __builtin_amdgcn_mfma_f32_16x16x32_f16(afrag, bfB, accB[ct], 0, 0, 0);
        }
    }
    __syncthreads();   // all LDS reads done before caller restages
    #pragma unroll
    for (int q2 = 0; q2 < 4; ++q2) {
        const int gr2 = r0 + wave * 16 + lg * 4 + q2;
        if (gr2 < M) {
            #pragma unroll
            for (int ct = 0; ct < 8; ++ct) {
                const int col = ct * 16 + l15;
                Y[(size_t)gr2 * 256 + col]       = f16_of(accA[ct][q2]);
                Y[(size_t)gr2 * 256 + 128 + col] = f16_of(accB[ct][q2]);
            }
        }
    }
}

// ================= cooperative: CSR build + all projections =================
__global__ __launch_bounds__(256, 2)
void csr_gemm(const int* __restrict__ edges, const float* __restrict__ hidden,
              const float* __restrict__ rela,
              const float* __restrict__ Ws, const float* __restrict__ Wr,
              const float* __restrict__ Wqr_w, const float* __restrict__ Wh,
              const float* __restrict__ bias, const int* __restrict__ q_rel,
              ushort_t* __restrict__ Wt4, unsigned* __restrict__ rec,
              int* __restrict__ obj, int* __restrict__ count, int* __restrict__ bsum,
              int* __restrict__ start, int* __restrict__ cursor,
              unsigned* __restrict__ sorted,
              ushort_t* __restrict__ combo, ushort_t* __restrict__ hrcombo,
              ushort_t* __restrict__ qrb,
              int E, int N, int R, int B) {
    cg::grid_group grid = cg::this_grid();
    __shared__ ushort_t sWA[D * D];   // 32 KB
    __shared__ ushort_t sWB[D * D];   // 32 KB
    __shared__ ushort_t sX[64 * D];   // 16 KB  (total exactly 80 KB)
    int* sw = (int*)sX;               // scan scratch aliases sX
    const int t = threadIdx.x, bid = blockIdx.x, nb = gridDim.x;
    const int lane = t & 63, w = t >> 6;

    // ---- Phase A: weight transpose (blocks 0..3) + zero count ----
    if (bid < 4) {
        const float* src = bid == 0 ? Ws : bid == 1 ? Wr : bid == 2 ? Wqr_w : Wh;
        ushort_t* dst = Wt4 + (size_t)bid * (D * D);
        for (int i = t; i < D * D; i += BLK) {
            const int k = i >> 7, col = i & 127;
            sWA[col * D + k] = f16_of(src[i]);
        }
        __syncthreads();
        const uint4* s8 = (const uint4*)sWA;
        uint4* d8 = (uint4*)dst;
        for (int i = t; i < D * D / 8; i += BLK) d8[i] = s8[i];
    } else {
        for (int i = (bid - 4) * BLK + t; i < N; i += (nb - 4) * BLK) count[i] = 0;
    }
    grid.sync();

    // ---- Phase B: pack edges + histogram ----
    {
        const uint2* e2 = (const uint2*)edges;
        for (int e = bid * BLK + t; e < E; e += nb * BLK) {
            const unsigned r_idx = e2[e * 3 + 0].x;
            const unsigned rel   = e2[e * 3 + 1].x;
            const uint2 so       = e2[e * 3 + 2];
            rec[e] = so.x | (rel << 16) | (r_idx << 25);
            obj[e] = (int)so.y;
            atomicAdd(&count[so.y], 1);
        }
    }
    grid.sync();

    // ---- Phase C1: per-256-chunk sums ----
    const int G2 = (N + BLK - 1) / BLK;
    for (int ch = bid; ch < G2; ch += nb) {
        const int i = ch * BLK + t;
        int v = (i < N) ? count[i] : 0;
        #pragma unroll
        for (int off = 32; off > 0; off >>= 1) v += __shfl_xor(v, off, 64);
        if (lane == 0) sw[w] = v;
        __syncthreads();
        if (t == 0) bsum[ch] = sw[0] + sw[1] + sw[2] + sw[3];
        __syncthreads();
    }
    grid.sync();

    // ---- Phase C2: block 0 exclusive-scans bsum[0..G2) ----
    if (bid == 0) {
        const int v = (t < G2) ? bsum[t] : 0;
        int x = v;
        #pragma unroll
        for (int off = 1; off < 64; off <<= 1) {
            int y = __shfl_up(x, off, 64);
            if (lane >= off) x += y;
        }
        if (lane == 63) sw[w] = x;
        __syncthreads();
        if (t == 0) { int s = 0; for (int k = 0; k < 4; ++k) { int tmp = sw[k]; sw[k] = s; s += tmp; } }
        __syncthreads();
        x += sw[w];
        if (t < G2) bsum[t] = x - v;
    }
    grid.sync();

    // ---- Phase C3: per-chunk exclusive scan + global offset ----
    for (int ch = bid; ch < G2; ch += nb) {
        const int i = ch * BLK + t;
        const int v = (i < N) ? count[i] : 0;
        int x = v;
        #pragma unroll
        for (int off = 1; off < 64; off <<= 1) {
            int y = __shfl_up(x, off, 64);
            if (lane >= off) x += y;
        }
        if (lane == 63) sw[w] = x;
        __syncthreads();
        if (t == 0) { int s = 0; for (int k = 0; k < 4; ++k) { int tmp = sw[k]; sw[k] = s; s += tmp; } }
        __syncthreads();
        x += sw[w];
        const int excl = x - v + bsum[ch];
        if (i < N) {
            start[i] = excl;
            cursor[i] = excl;
            if (i == N - 1) start[N] = excl + v;
        }
        __syncthreads();
    }
    grid.sync();

    // ---- Phase D/E: scatter (first quarter) || GEMM projections (rest) ----
    const int SC = nb >> 2;
    const int TB = (N + 63) / 64;
    const int RB = (R + 63) / 64;
    if (bid < SC) {
        for (int e = bid * BLK + t; e < E; e += SC * BLK) {
            const int pos = atomicAdd(&cursor[obj[e]], 1);
            sorted[pos] = rec[e];
        }
        if (bid <= RB) {
            __syncthreads();
            if (bid < RB) {          // hrcombo = [rela@Wh | rela@Wr]
                stage_w(sWA, Wt4 + 3 * D * D, t);
                stage_w(sWB, Wt4 + 1 * D * D, t);
                __syncthreads();
                dual_tile(rela, bid * 64, R, hrcombo, sWA, sWB, sX, t);
            } else {                 // qrb = rela[q_rel]@Wqr + bias
                stage_w(sWA, Wt4 + 2 * D * D, t);
                __syncthreads();
                const int l15 = lane & 15, lg = lane >> 4;
                const int wave = w;
                stage_x(sX, rela, q_rel, 0, B, t);
                __syncthreads();
                f32x4 acc[8];
                #pragma unroll
                for (int ct = 0; ct < 8; ++ct) acc[ct] = (f32x4){0.f, 0.f, 0.f, 0.f};
                #pragma unroll
                for (int kc = 0; kc < 4; ++kc) {
                    const int koff = kc * 64 + lg * 16;
                    const int arow = wave * 16 + l15;
                    const f16x8 afrag = *(const f16x8*)((char*)sX + arow * 256 + (koff ^ ((arow & 7) << 4)));
                    #pragma unroll
                    for (int ct = 0; ct < 8; ++ct) {
                        const int col = ct * 16 + l15;
                        const f16x8 bf = *(const f16x8*)((char*)sWA + col * 256 + (koff ^ ((col & 7) << 4)));
                        acc[ct] = __builtin_amdgcn_mfma_f32_16x16x32_f16(afrag, bf, acc[ct], 0, 0, 0);
                    }
                }
                #pragma unroll
                for (int q2 = 0; q2 < 4; ++q2) {
                    const int gr2 = wave * 16 + lg * 4 + q2;
                    if (gr2 < B) {
                        #pragma unroll
                        for (int ct = 0; ct < 8; ++ct) {
                            const int col = ct * 16 + l15;
                            qrb[(size_t)gr2 * 128 + col] = f16_of(acc[ct][q2] + bias[col]);
                        }
                    }
                }
            }
        }
    } else {                          // combo = [hidden@Wh | hidden@Ws]
        stage_w(sWA, Wt4 + 3 * D * D, t);
        stage_w(sWB, Wt4, t);
        __syncthreads();
        for (int tile = bid - SC; tile < TB; tile += nb - SC)
            dual_tile(hidden, tile * 64, N, combo, sWA, sWB, sX, t);
    }
}

// ------- per-node aggregation, fp16 packed accum: out = relu(sum a*(hw+rw)) -------
__global__ void agg_v10(const unsigned* __restrict__ sorted, const int* __restrict__ start,
                        const __half* __restrict__ combo,    // [N][256]: hw | hs_proj
                        const __half* __restrict__ hrcombo,  // [R][256]: rw | hr_proj
                        const __half* __restrict__ qrb,      // [B][128]: qr_proj
                        const float* __restrict__ Wa,
                        float* __restrict__ out, int N) {
    const int gtid = blockIdx.x * blockDim.x + threadIdx.x;
    const int wave = gtid >> 6;
    const int lane = threadIdx.x & 63;
    const int nwaves = (gridDim.x * blockDim.x) >> 6;
    const int grp = lane >> 4;        // 0..3 : edge slot within wave
    const int sl  = lane & 15;        // 0..15
    const int c   = sl * 8;           // 8 cols per lane
    __half2 wah[4];
    {
        const float4 w0 = *(const float4*)(Wa + c);
        const float4 w1 = *(const float4*)(Wa + c + 4);
        wah[0] = __floats2half2_rn(w0.x, w0.y);
        wah[1] = __floats2half2_rn(w0.z, w0.w);
        wah[2] = __floats2half2_rn(w1.x, w1.y);
        wah[3] = __floats2half2_rn(w1.z, w1.w);
    }
    const __half2 zero2 = __floats2half2_rn(0.f, 0.f);
    for (int n = wave; n < N; n += nwaves) {
        const int e0 = start[n], e1 = start[n + 1];
        __half2 a0 = zero2, a1 = zero2, a2 = zero2, a3 = zero2;
        int e = e0 + grp;
        unsigned nrec = (e < e1) ? sorted[e] : 0u;
        for (; e < e1; e += 4) {
            const unsigned rc = nrec;
            if (e + 4 < e1) nrec = sorted[e + 4];
            const int sub  = rc & 0xFFFF;
            const int rel  = (rc >> 16) & 0x1FF;
            const int ridx = rc >> 25;
            const H8 uhw  = *(const H8*)(combo + (size_t)sub * 256 + c);
            const H8 uhsp = *(const H8*)(combo + (size_t)sub * 256 + 128 + c);
            const H8 urw  = *(const H8*)(hrcombo + (size_t)rel * 256 + c);
            const H8 uhrp = *(const H8*)(hrcombo + (size_t)rel * 256 + 128 + c);
            const H8 uqrp = *(const H8*)(qrb + (size_t)ridx * 128 + c);
            __half2 d2 = zero2;
            #pragma unroll
            for (int j = 0; j < 4; ++j) {
                const __half2 p = hmax2(__hadd2(__hadd2(uhsp.h[j], uhrp.h[j]), uqrp.h[j]), zero2);
                d2 = __hfma2(p, wah[j], d2);
            }
            float part = __low2float(d2) + __high2float(d2);
            #pragma unroll
            for (int off = 8; off > 0; off >>= 1) part += __shfl_xor(part, off, 64);
            const float alpha = 1.f / (1.f + __expf(-part));
            const __half2 al2 = __float2half2_rn(alpha);
            a0 = __hfma2(__hadd2(uhw.h[0], urw.h[0]), al2, a0);
            a1 = __hfma2(__hadd2(uhw.h[1], urw.h[1]), al2, a1);
            a2 = __hfma2(__hadd2(uhw.h[2], urw.h[2]), al2, a2);
            a3 = __hfma2(__hadd2(uhw.h[3], urw.h[3]), al2, a3);
        }
        __half2 aa[4] = {a0, a1, a2, a3};
        #pragma unroll
        for (int j = 0; j < 4; ++j) {   // combine the 4 edge slots
            unsigned u = __builtin_bit_cast(unsigned, aa[j]);
            __half2 s = __hadd2(aa[j], __builtin_bit_cast(__half2, __shfl_xor(u, 16, 64)));
            u = __builtin_bit_cast(unsigned, s);
            aa[j] = __hadd2(s, __builtin_bit_cast(__half2, __shfl_xor(u, 32, 64)));
        }
        if (grp == 0) {
            const float4 o0 = make_float4(fmaxf(__low2float(aa[0]), 0.f), fmaxf(__high2float(aa[0]), 0.f),
                                          fmaxf(__low2float(aa[1]), 0.f), fmaxf(__high2float(aa[1]), 0.f));
            const float4 o1 = make_float4(fmaxf(__low2float(aa[2]), 0.f), fmaxf(__high2float(aa[2]), 0.f),
                                          fmaxf(__low2float(aa[3]), 0.f), fmaxf(__high2float(aa[3]), 0.f));
            *(float4*)(out + (size_t)n * D + c)     = o0;
            *(float4*)(out + (size_t)n * D + c + 4) = o1;
        }
    }
}

extern "C" void kernel_launch(void* const* d_in, const int* in_sizes, int n_in,
                              void* d_out, int out_size, void* d_ws, size_t ws_size,
                              hipStream_t stream) {
    const int*   q_rel  = (const int*)d_in[0];
    const float* hidden = (const float*)d_in[1];
    const int*   edges  = (const int*)d_in[2];
    const float* rela   = (const float*)d_in[3];
    const float* Ws     = (const float*)d_in[4];
    const float* Wr     = (const float*)d_in[5];
    const float* Wqr_w  = (const float*)d_in[6];
    const float* Wqr_b  = (const float*)d_in[7];
    const float* Wa     = (const float*)d_in[8];
    const float* Wh     = (const float*)d_in[9];

    int B = in_sizes[0];
    int N = in_sizes[1] / D;
    int E = in_sizes[2] / 6;
    int R = in_sizes[3] / D;

    ushort_t* combo   = (ushort_t*)d_ws;                 // N*256 fp16: hw | hs_proj
    ushort_t* hrcombo = combo + (size_t)N * 256;         // R*256 fp16: rw | hr_proj
    ushort_t* qrb     = hrcombo + (size_t)R * 256;       // B*128 fp16
    ushort_t* Wt4     = qrb + (size_t)B * 128;           // 4*128*128 fp16
    int* count  = (int*)(Wt4 + 4 * D * D);               // N
    int* bsum   = count + N;                             // 256
    int* start  = bsum + 256;                            // N+1
    int* cursor = start + N + 1;                         // N
    unsigned* rec    = (unsigned*)(cursor + N);          // E
    int*      obj    = (int*)(rec + E);                  // E
    unsigned* sorted = (unsigned*)(obj + E);             // E

    // cooperative CSR + projections (grid clamped to guaranteed co-residency)
    int maxb = 0;
    (void)hipOccupancyMaxActiveBlocksPerMultiprocessor(&maxb, (const void*)csr_gemm, BLK, 0);
    if (maxb < 1) maxb = 1;
    int grid = maxb * 256;            // 256 CUs on MI355X
    if (grid > 512) grid = 512;

    void* args[] = {
        (void*)&edges, (void*)&hidden, (void*)&rela,
        (void*)&Ws, (void*)&Wr, (void*)&Wqr_w, (void*)&Wh,
        (void*)&Wqr_b, (void*)&q_rel,
        (void*)&Wt4, (void*)&rec, (void*)&obj, (void*)&count, (void*)&bsum,
        (void*)&start, (void*)&cursor, (void*)&sorted,
        (void*)&combo, (void*)&hrcombo, (void*)&qrb,
        (void*)&E, (void*)&N, (void*)&R, (void*)&B
    };
    (void)hipLaunchCooperativeKernel((void*)csr_gemm, dim3(grid), dim3(BLK),
                                     args, 0, stream);

    // final: gather-aggregate + relu -> d_out
    agg_v10<<<2048, 256, 0, stream>>>(sorted, start, (const __half*)combo,
                                      (const __half*)hrcombo, (const __half*)qrb, Wa,
                                      (float*)d_out, N);
}

// Round 13
// 130.693 us; speedup vs baseline: 2.9997x; 2.9997x over previous
//
#include <hip/hip_runtime.h>
#include <hip/hip_fp16.h>
#include <math.h>
#include <stdint.h>

#define D 128
typedef __attribute__((ext_vector_type(8))) _Float16 f16x8;
typedef __attribute__((ext_vector_type(4))) float f32x4;
typedef unsigned short ushort_t;

__device__ inline unsigned pack_f16(float a, float b) {
    __half2 h = __floats2half2_rn(a, b);
    return __builtin_bit_cast(unsigned, h);
}
__device__ inline ushort_t f16_of(float f) {
    __half h = __float2half_rn(f);
    return __builtin_bit_cast(ushort_t, h);
}
__device__ inline __half2 hmax2(__half2 a, __half2 b) {
    unsigned ua = __builtin_bit_cast(unsigned, a);
    unsigned ub = __builtin_bit_cast(unsigned, b);
    unsigned r;
    asm("v_pk_max_f16 %0, %1, %2" : "=v"(r) : "v"(ua), "v"(ub));
    return __builtin_bit_cast(__half2, r);
}

struct __align__(16) H8 { __half2 h[4]; };

// ------------- fused: W->W^T fp16 prep (blocks 0..3) + edge pack/hist (blocks 4+) -------
// rec = sub:16 | rel:9 | r_idx:7
__global__ void pack_prep(const int* __restrict__ edges, unsigned* __restrict__ rec,
                          int* __restrict__ obj, int* __restrict__ count, int E,
                          const float* __restrict__ W0, const float* __restrict__ W1,
                          const float* __restrict__ W2, const float* __restrict__ W3,
                          ushort_t* __restrict__ Wt4) {
    __shared__ ushort_t sT[D * D];
    const int t = threadIdx.x;
    if (blockIdx.x < 4) {   // transpose+convert one weight matrix
        const float* src = blockIdx.x == 0 ? W0 : blockIdx.x == 1 ? W1 : blockIdx.x == 2 ? W2 : W3;
        ushort_t* dst = Wt4 + (size_t)blockIdx.x * (D * D);
        for (int i = t; i < D * D; i += 256) {
            const int k = i >> 7, col = i & 127;
            sT[col * D + k] = f16_of(src[i]);
        }
        __syncthreads();
        const uint4* s8 = (const uint4*)sT;
        uint4* d8 = (uint4*)dst;
        for (int i = t; i < D * D / 8; i += 256) d8[i] = s8[i];
    } else {                // pack edges + histogram
        const int i0 = (blockIdx.x - 4) * blockDim.x + t;
        const int stride = (gridDim.x - 4) * blockDim.x;
        const uint2* e2 = (const uint2*)edges;
        for (int e = i0; e < E; e += stride) {
            const unsigned r_idx = e2[e * 3 + 0].x;
            const unsigned rel   = e2[e * 3 + 1].x;
            const uint2 so       = e2[e * 3 + 2];     // .x=sub .y=obj
            rec[e] = so.x | (rel << 16) | (r_idx << 25);
            obj[e] = (int)so.y;
            atomicAdd(&count[so.y], 1);
        }
    }
}

// ---------------- 2-phase exclusive scan ----------------
__global__ void scan_partial(const int* __restrict__ count, int* __restrict__ bsum, int M) {
    __shared__ int wsum[16];
    const int t = threadIdx.x, lane = t & 63, w = t >> 6;
    const int i = blockIdx.x * 1024 + t;
    int v = (i < M) ? count[i] : 0;
    #pragma unroll
    for (int off = 32; off > 0; off >>= 1) v += __shfl_xor(v, off, 64);
    if (lane == 0) wsum[w] = v;
    __syncthreads();
    if (w == 0) {
        int s = (lane < 16) ? wsum[lane] : 0;
        #pragma unroll
        for (int off = 8; off > 0; off >>= 1) s += __shfl_xor(s, off, 16);
        if (lane == 0) bsum[blockIdx.x] = s;
    }
}

__global__ void scan_final(const int* __restrict__ count, const int* __restrict__ bsum,
                           int* __restrict__ start, int* __restrict__ cursor, int M, int G) {
    __shared__ int wsum[16];
    __shared__ int sboff;
    const int t = threadIdx.x, lane = t & 63, w = t >> 6;
    const int i = blockIdx.x * 1024 + t;
    const int v = (i < M) ? count[i] : 0;
    if (w == 0) {
        int bv = (lane < G) ? bsum[lane] : 0;
        int bx = bv;
        #pragma unroll
        for (int off = 1; off < 64; off <<= 1) {
            int y = __shfl_up(bx, off, 64);
            if (lane >= off) bx += y;
        }
        if (lane == (blockIdx.x & 63)) sboff = bx - bv;
    }
    int x = v;
    #pragma unroll
    for (int off = 1; off < 64; off <<= 1) {
        int y = __shfl_up(x, off, 64);
        if (lane >= off) x += y;
    }
    if (lane == 63) wsum[w] = x;
    __syncthreads();
    if (w == 0) {
        int s = (lane < 16) ? wsum[lane] : 0;
        int xs = s;
        #pragma unroll
        for (int off = 1; off < 16; off <<= 1) {
            int y = __shfl_up(xs, off, 64);
            if (lane >= off) xs += y;
        }
        if (lane < 16) wsum[lane] = xs - s;
    }
    __syncthreads();
    const int excl = x - v + wsum[w] + sboff;
    if (i < M) {
        start[i] = excl;
        cursor[i] = excl;
        if (i == M - 1) start[M] = excl + v;
    }
}

// ---------------- scatter packed recs into CSR order ----------------
__global__ void scatter2(const unsigned* __restrict__ rec, const int* __restrict__ obj,
                         int* __restrict__ cursor, unsigned* __restrict__ sorted, int E) {
    const int i = blockIdx.x * blockDim.x + threadIdx.x;
    const int stride = gridDim.x * blockDim.x;
    for (int e = i; e < E; e += stride) {
        const int pos = atomicAdd(&cursor[obj[e]], 1);
        sorted[pos] = rec[e];
    }
}

// ---- LDS staging helpers (XOR-swizzled layout, 256B rows) ----
__device__ inline void stage_w(ushort_t* sW, const ushort_t* Wt, int t) {
    const uint4* src = (const uint4*)Wt;
    for (int s = t; s < 2048; s += 256) {
        const int col = s >> 4;
        const int off = (s & 15) * 16;
        *(uint4*)((char*)sW + col * 256 + (off ^ ((col & 7) << 4))) = src[s];
    }
}
__device__ inline void stage_x(ushort_t* sX, const float* X, const int* rowidx,
                               int r0, int M, int t) {
    const int row = t >> 2, q = t & 3;
    const int gr = r0 + row;
    if (gr < M) {
        const int src = rowidx ? rowidx[gr] : gr;
        const float* xp = X + (size_t)src * D + q * 32;
        #pragma unroll
        for (int s = 0; s < 4; ++s) {
            const float4 v0 = *(const float4*)(xp + s * 8);
            const float4 v1 = *(const float4*)(xp + s * 8 + 4);
            uint4 pk;
            pk.x = pack_f16(v0.x, v0.y); pk.y = pack_f16(v0.z, v0.w);
            pk.z = pack_f16(v1.x, v1.y); pk.w = pack_f16(v1.z, v1.w);
            const int off = q * 64 + s * 16;
            *(uint4*)((char*)sX + row * 256 + (off ^ ((row & 7) << 4))) = pk;
        }
    }
}

// ---------------- all projections in one launch ----------------
// blocks [0,TB):       combo   = [hidden@Wh | hidden@Ws]
// blocks [TB,TB+RB):   hrcombo = [rela@Wh   | rela@Wr]
// block  TB+RB:        qrb     = rela[q_rel]@Wqr + bias
__global__ __launch_bounds__(256, 2)
void gemm_all(const float* __restrict__ hidden, const float* __restrict__ rela,
              const ushort_t* __restrict__ Wt4, const float* __restrict__ bias,
              const int* __restrict__ q_rel,
              ushort_t* __restrict__ combo, ushort_t* __restrict__ hrcombo,
              ushort_t* __restrict__ qrb, int N, int R, int B, int TB, int RB) {
    __shared__ ushort_t sWA[D * D];  // 32 KB
    __shared__ ushort_t sWB[D * D];  // 32 KB
    __shared__ ushort_t sX[64 * D];  // 16 KB
    const int t = threadIdx.x;
    const int wave = t >> 6, lane = t & 63;
    const int l15 = lane & 15, lg = lane >> 4;
    const int bid = blockIdx.x;

    const bool qpath = (bid == TB + RB);
    const float* X   = (bid < TB) ? hidden : rela;
    const int    M   = (bid < TB) ? N : (qpath ? B : R);
    const int    r0  = (bid < TB) ? bid * 64 : (qpath ? 0 : (bid - TB) * 64);
    ushort_t*    Y   = (bid < TB) ? combo : (qpath ? qrb : hrcombo);

    if (!qpath) {
        stage_w(sWA, Wt4 + 3 * D * D, t);                         // Wh^T
        stage_w(sWB, (bid < TB) ? Wt4 : (Wt4 + D * D), t);        // Ws^T or Wr^T
        stage_x(sX, X, nullptr, r0, M, t);
        __syncthreads();
        f32x4 accA[8], accB[8];
        #pragma unroll
        for (int ct = 0; ct < 8; ++ct) {
            accA[ct] = (f32x4){0.f, 0.f, 0.f, 0.f};
            accB[ct] = (f32x4){0.f, 0.f, 0.f, 0.f};
        }
        #pragma unroll
        for (int kc = 0; kc < 4; ++kc) {
            const int koff = kc * 64 + lg * 16;
            const int arow = wave * 16 + l15;
            const f16x8 afrag = *(const f16x8*)((char*)sX + arow * 256 + (koff ^ ((arow & 7) << 4)));
            #pragma unroll
            for (int ct = 0; ct < 8; ++ct) {
                const int col = ct * 16 + l15;
                const int sw = koff ^ ((col & 7) << 4);
                const f16x8 bfA = *(const f16x8*)((char*)sWA + col * 256 + sw);
                const f16x8 bfB = *(const f16x8*)((char*)sWB + col * 256 + sw);
                accA[ct] = __builtin_amdgcn_mfma_f32_16x16x32_f16(afrag, bfA, accA[ct], 0, 0, 0);
                accB[ct] = __builtin_amdgcn_mfma_f32_16x16x32_f16(afrag, bfB, accB[ct], 0, 0, 0);
            }
        }
        #pragma unroll
        for (int q2 = 0; q2 < 4; ++q2) {
            const int gr2 = r0 + wave * 16 + lg * 4 + q2;
            if (gr2 < M) {
                #pragma unroll
                for (int ct = 0; ct < 8; ++ct) {
                    const int col = ct * 16 + l15;
                    Y[(size_t)gr2 * 256 + col]       = f16_of(accA[ct][q2]);   // @Wh
                    Y[(size_t)gr2 * 256 + 128 + col] = f16_of(accB[ct][q2]);   // @Ws / @Wr
                }
            }
        }
    } else {
        stage_w(sWA, Wt4 + 2 * D * D, t);                         // Wqr^T
        stage_x(sX, X, q_rel, 0, M, t);
        __syncthreads();
        f32x4 acc[8];
        #pragma unroll
        for (int ct = 0; ct < 8; ++ct) acc[ct] = (f32x4){0.f, 0.f, 0.f, 0.f};
        #pragma unroll
        for (int kc = 0; kc < 4; ++kc) {
            const int koff = kc * 64 + lg * 16;
            const int arow = wave * 16 + l15;
            const f16x8 afrag = *(const f16x8*)((char*)sX + arow * 256 + (koff ^ ((arow & 7) << 4)));
            #pragma unroll
            for (int ct = 0; ct < 8; ++ct) {
                const int col = ct * 16 + l15;
                const f16x8 bf = *(const f16x8*)((char*)sWA + col * 256 + (koff ^ ((col & 7) << 4)));
                acc[ct] = __builtin_amdgcn_mfma_f32_16x16x32_f16(afrag, bf, acc[ct], 0, 0, 0);
            }
        }
        #pragma unroll
        for (int q2 = 0; q2 < 4; ++q2) {
            const int gr2 = wave * 16 + lg * 4 + q2;
            if (gr2 < M) {
                #pragma unroll
                for (int ct = 0; ct < 8; ++ct) {
                    const int col = ct * 16 + l15;
                    Y[(size_t)gr2 * 128 + col] = f16_of(acc[ct][q2] + bias[col]);
                }
            }
        }
    }
}

// ------- per-node aggregation, fp16 packed accum: out = relu(sum a*(hw+rw)) -------
__global__ void agg_v10(const unsigned* __restrict__ sorted, const int* __restrict__ start,
                        const __half* __restrict__ combo,    // [N][256]: hw | hs_proj
                        const __half* __restrict__ hrcombo,  // [R][256]: rw | hr_proj
                        const __half* __restrict__ qrb,      // [B][128]: qr_proj
                        const float* __restrict__ Wa,
                        float* __restrict__ out, int N) {
    const int gtid = blockIdx.x * blockDim.x + threadIdx.x;
    const int wave = gtid >> 6;
    const int lane = threadIdx.x & 63;
    const int nwaves = (gridDim.x * blockDim.x) >> 6;
    const int grp = lane >> 4;        // 0..3 : edge slot within wave
    const int sl  = lane & 15;        // 0..15
    const int c   = sl * 8;           // 8 cols per lane
    __half2 wah[4];
    {
        const float4 w0 = *(const float4*)(Wa + c);
        const float4 w1 = *(const float4*)(Wa + c + 4);
        wah[0] = __floats2half2_rn(w0.x, w0.y);
        wah[1] = __floats2half2_rn(w0.z, w0.w);
        wah[2] = __floats2half2_rn(w1.x, w1.y);
        wah[3] = __floats2half2_rn(w1.z, w1.w);
    }
    const __half2 zero2 = __floats2half2_rn(0.f, 0.f);
    for (int n = wave; n < N; n += nwaves) {
        const int e0 = start[n], e1 = start[n + 1];
        __half2 a0 = zero2, a1 = zero2, a2 = zero2, a3 = zero2;
        int e = e0 + grp;
        unsigned nrec = (e < e1) ? sorted[e] : 0u;
        for (; e < e1; e += 4) {
            const unsigned rc = nrec;
            if (e + 4 < e1) nrec = sorted[e + 4];   // only the index word is prefetched
            const int sub  = rc & 0xFFFF;
            const int rel  = (rc >> 16) & 0x1FF;
            const int ridx = rc >> 25;
            const H8 uhw  = *(const H8*)(combo + (size_t)sub * 256 + c);
            const H8 uhsp = *(const H8*)(combo + (size_t)sub * 256 + 128 + c);
            const H8 urw  = *(const H8*)(hrcombo + (size_t)rel * 256 + c);
            const H8 uhrp = *(const H8*)(hrcombo + (size_t)rel * 256 + 128 + c);
            const H8 uqrp = *(const H8*)(qrb + (size_t)ridx * 128 + c);
            __half2 d2 = zero2;
            #pragma unroll
            for (int j = 0; j < 4; ++j) {
                const __half2 p = hmax2(__hadd2(__hadd2(uhsp.h[j], uhrp.h[j]), uqrp.h[j]), zero2);
                d2 = __hfma2(p, wah[j], d2);
            }
            float part = __low2float(d2) + __high2float(d2);
            #pragma unroll
            for (int off = 8; off > 0; off >>= 1) part += __shfl_xor(part, off, 64);
            const float alpha = 1.f / (1.f + __expf(-part));
            const __half2 al2 = __float2half2_rn(alpha);
            a0 = __hfma2(__hadd2(uhw.h[0], urw.h[0]), al2, a0);
            a1 = __hfma2(__hadd2(uhw.h[1], urw.h[1]), al2, a1);
            a2 = __hfma2(__hadd2(uhw.h[2], urw.h[2]), al2, a2);
            a3 = __hfma2(__hadd2(uhw.h[3], urw.h[3]), al2, a3);
        }
        __half2 aa[4] = {a0, a1, a2, a3};
        #pragma unroll
        for (int j = 0; j < 4; ++j) {   // combine the 4 edge slots
            unsigned u = __builtin_bit_cast(unsigned, aa[j]);
            __half2 s = __hadd2(aa[j], __builtin_bit_cast(__half2, __shfl_xor(u, 16, 64)));
            u = __builtin_bit_cast(unsigned, s);
            aa[j] = __hadd2(s, __builtin_bit_cast(__half2, __shfl_xor(u, 32, 64)));
        }
        if (grp == 0) {
            const float4 o0 = make_float4(fmaxf(__low2float(aa[0]), 0.f), fmaxf(__high2float(aa[0]), 0.f),
                                          fmaxf(__low2float(aa[1]), 0.f), fmaxf(__high2float(aa[1]), 0.f));
            const float4 o1 = make_float4(fmaxf(__low2float(aa[2]), 0.f), fmaxf(__high2float(aa[2]), 0.f),
                                          fmaxf(__low2float(aa[3]), 0.f), fmaxf(__high2float(aa[3]), 0.f));
            *(float4*)(out + (size_t)n * D + c)     = o0;
            *(float4*)(out + (size_t)n * D + c + 4) = o1;
        }
    }
}

extern "C" void kernel_launch(void* const* d_in, const int* in_sizes, int n_in,
                              void* d_out, int out_size, void* d_ws, size_t ws_size,
                              hipStream_t stream) {
    const int*   q_rel  = (const int*)d_in[0];
    const float* hidden = (const float*)d_in[1];
    const int*   edges  = (const int*)d_in[2];
    const float* rela   = (const float*)d_in[3];
    const float* Ws     = (const float*)d_in[4];
    const float* Wr     = (const float*)d_in[5];
    const float* Wqr_w  = (const float*)d_in[6];
    const float* Wqr_b  = (const float*)d_in[7];
    const float* Wa     = (const float*)d_in[8];
    const float* Wh     = (const float*)d_in[9];

    const int B = in_sizes[0];
    const int N = in_sizes[1] / D;
    const int E = in_sizes[2] / 6;
    const int R = in_sizes[3] / D;

    ushort_t* combo   = (ushort_t*)d_ws;                 // N*256 fp16: hw | hs_proj
    ushort_t* hrcombo = combo + (size_t)N * 256;         // R*256 fp16: rw | hr_proj
    ushort_t* qrb     = hrcombo + (size_t)R * 256;       // B*128 fp16
    ushort_t* Wt4     = qrb + (size_t)B * 128;           // 4*128*128 fp16: Ws,Wr,Wqr,Wh ^T
    int* count  = (int*)(Wt4 + 4 * D * D);               // N
    int* bsum   = count + N;                             // 64
    int* start  = bsum + 64;                             // N+1
    int* cursor = start + N + 1;                         // N
    unsigned* rec    = (unsigned*)(cursor + N);          // E
    int*      obj    = (int*)(rec + E);                  // E
    unsigned* sorted = (unsigned*)(obj + E);             // E

    // CSR build (+ fused weight transpose in blocks 0..3)
    (void)hipMemsetAsync(count, 0, (size_t)N * sizeof(int), stream);
    pack_prep<<<1028, 256, 0, stream>>>(edges, rec, obj, count, E,
                                        Ws, Wr, Wqr_w, Wh, Wt4);
    const int G = (N + 1023) / 1024;
    scan_partial<<<G, 1024, 0, stream>>>(count, bsum, N);
    scan_final<<<G, 1024, 0, stream>>>(count, bsum, start, cursor, N, G);
    scatter2<<<1024, 256, 0, stream>>>(rec, obj, cursor, sorted, E);

    // all projections in one launch
    const int TB = (N + 63) / 64;
    const int RB = (R + 63) / 64;
    gemm_all<<<TB + RB + 1, 256, 0, stream>>>(hidden, rela, Wt4, Wqr_b, q_rel,
                                              combo, hrcombo, qrb, N, R, B, TB, RB);

    // final: gather-aggregate + relu -> d_out
    agg_v10<<<2048, 256, 0, stream>>>(sorted, start, (const __half*)combo,
                                      (const __half*)hrcombo, (const __half*)qrb, Wa,
                                      (float*)d_out, N);
}

// Round 14
// 118.994 us; speedup vs baseline: 3.2946x; 1.0983x over previous
//
#include <hip/hip_runtime.h>
#include <hip/hip_fp16.h>
#include <math.h>
#include <stdint.h>

#define D 128
typedef __attribute__((ext_vector_type(8))) _Float16 f16x8;
typedef __attribute__((ext_vector_type(4))) float f32x4;
typedef unsigned short ushort_t;

__device__ inline unsigned pack_f16(float a, float b) {
    __half2 h = __floats2half2_rn(a, b);
    return __builtin_bit_cast(unsigned, h);
}
__device__ inline ushort_t f16_of(float f) {
    __half h = __float2half_rn(f);
    return __builtin_bit_cast(ushort_t, h);
}
__device__ inline __half2 hmax2(__half2 a, __half2 b) {
    unsigned ua = __builtin_bit_cast(unsigned, a);
    unsigned ub = __builtin_bit_cast(unsigned, b);
    unsigned r;
    asm("v_pk_max_f16 %0, %1, %2" : "=v"(r) : "v"(ua), "v"(ub));
    return __builtin_bit_cast(__half2, r);
}

struct __align__(16) H8 { __half2 h[4]; };

// ------------- fused: W->W^T fp16 prep (blocks 0..3) + edge pack/hist (blocks 4+) -------
// rec = sub:16 | rel:9 | r_idx:7
__global__ void pack_prep(const int* __restrict__ edges, unsigned* __restrict__ rec,
                          int* __restrict__ obj, int* __restrict__ count, int E,
                          const float* __restrict__ W0, const float* __restrict__ W1,
                          const float* __restrict__ W2, const float* __restrict__ W3,
                          ushort_t* __restrict__ Wt4) {
    __shared__ ushort_t sT[D * D];
    const int t = threadIdx.x;
    if (blockIdx.x < 4) {   // transpose+convert one weight matrix
        const float* src = blockIdx.x == 0 ? W0 : blockIdx.x == 1 ? W1 : blockIdx.x == 2 ? W2 : W3;
        ushort_t* dst = Wt4 + (size_t)blockIdx.x * (D * D);
        for (int i = t; i < D * D; i += 256) {
            const int k = i >> 7, col = i & 127;
            sT[col * D + k] = f16_of(src[i]);
        }
        __syncthreads();
        const uint4* s8 = (const uint4*)sT;
        uint4* d8 = (uint4*)dst;
        for (int i = t; i < D * D / 8; i += 256) d8[i] = s8[i];
    } else {                // pack edges + histogram
        const int i0 = (blockIdx.x - 4) * blockDim.x + t;
        const int stride = (gridDim.x - 4) * blockDim.x;
        const uint2* e2 = (const uint2*)edges;
        for (int e = i0; e < E; e += stride) {
            const unsigned r_idx = e2[e * 3 + 0].x;
            const unsigned rel   = e2[e * 3 + 1].x;
            const uint2 so       = e2[e * 3 + 2];     // .x=sub .y=obj
            rec[e] = so.x | (rel << 16) | (r_idx << 25);
            obj[e] = (int)so.y;
            atomicAdd(&count[so.y], 1);
        }
    }
}

// ---------------- 2-phase exclusive scan ----------------
__global__ void scan_partial(const int* __restrict__ count, int* __restrict__ bsum, int M) {
    __shared__ int wsum[16];
    const int t = threadIdx.x, lane = t & 63, w = t >> 6;
    const int i = blockIdx.x * 1024 + t;
    int v = (i < M) ? count[i] : 0;
    #pragma unroll
    for (int off = 32; off > 0; off >>= 1) v += __shfl_xor(v, off, 64);
    if (lane == 0) wsum[w] = v;
    __syncthreads();
    if (w == 0) {
        int s = (lane < 16) ? wsum[lane] : 0;
        #pragma unroll
        for (int off = 8; off > 0; off >>= 1) s += __shfl_xor(s, off, 16);
        if (lane == 0) bsum[blockIdx.x] = s;
    }
}

__global__ void scan_final(const int* __restrict__ count, const int* __restrict__ bsum,
                           int* __restrict__ start, int* __restrict__ cursor, int M, int G) {
    __shared__ int wsum[16];
    __shared__ int sboff;
    const int t = threadIdx.x, lane = t & 63, w = t >> 6;
    const int i = blockIdx.x * 1024 + t;
    const int v = (i < M) ? count[i] : 0;
    if (w == 0) {
        int bv = (lane < G) ? bsum[lane] : 0;
        int bx = bv;
        #pragma unroll
        for (int off = 1; off < 64; off <<= 1) {
            int y = __shfl_up(bx, off, 64);
            if (lane >= off) bx += y;
        }
        if (lane == (blockIdx.x & 63)) sboff = bx - bv;
    }
    int x = v;
    #pragma unroll
    for (int off = 1; off < 64; off <<= 1) {
        int y = __shfl_up(x, off, 64);
        if (lane >= off) x += y;
    }
    if (lane == 63) wsum[w] = x;
    __syncthreads();
    if (w == 0) {
        int s = (lane < 16) ? wsum[lane] : 0;
        int xs = s;
        #pragma unroll
        for (int off = 1; off < 16; off <<= 1) {
            int y = __shfl_up(xs, off, 64);
            if (lane >= off) xs += y;
        }
        if (lane < 16) wsum[lane] = xs - s;
    }
    __syncthreads();
    const int excl = x - v + wsum[w] + sboff;
    if (i < M) {
        start[i] = excl;
        cursor[i] = excl;
        if (i == M - 1) start[M] = excl + v;
    }
}

// ---- LDS staging helpers (XOR-swizzled layout, 256B rows) ----
__device__ inline void stage_w(ushort_t* sW, const ushort_t* Wt, int t) {
    const uint4* src = (const uint4*)Wt;
    for (int s = t; s < 2048; s += 256) {
        const int col = s >> 4;
        const int off = (s & 15) * 16;
        *(uint4*)((char*)sW + col * 256 + (off ^ ((col & 7) << 4))) = src[s];
    }
}
__device__ inline void stage_x(ushort_t* sX, const float* X, const int* rowidx,
                               int r0, int M, int t) {
    const int row = t >> 2, q = t & 3;
    const int gr = r0 + row;
    if (gr < M) {
        const int src = rowidx ? rowidx[gr] : gr;
        const float* xp = X + (size_t)src * D + q * 32;
        #pragma unroll
        for (int s = 0; s < 4; ++s) {
            const float4 v0 = *(const float4*)(xp + s * 8);
            const float4 v1 = *(const float4*)(xp + s * 8 + 4);
            uint4 pk;
            pk.x = pack_f16(v0.x, v0.y); pk.y = pack_f16(v0.z, v0.w);
            pk.z = pack_f16(v1.x, v1.y); pk.w = pack_f16(v1.z, v1.w);
            const int off = q * 64 + s * 16;
            *(uint4*)((char*)sX + row * 256 + (off ^ ((row & 7) << 4))) = pk;
        }
    }
}

// dual-weight 64-row tile: Y[gr][0:128]=X@(sWA), Y[gr][128:256]=X@(sWB), fp16 out
__device__ inline void dual_tile(const float* X, int r0, int M, ushort_t* Y,
                                 ushort_t* sWA, ushort_t* sWB, ushort_t* sX, int t) {
    const int wave = t >> 6, lane = t & 63;
    const int l15 = lane & 15, lg = lane >> 4;
    stage_x(sX, X, nullptr, r0, M, t);
    __syncthreads();
    f32x4 accA[8], accB[8];
    #pragma unroll
    for (int ct = 0; ct < 8; ++ct) {
        accA[ct] = (f32x4){0.f, 0.f, 0.f, 0.f};
        accB[ct] = (f32x4){0.f, 0.f, 0.f, 0.f};
    }
    #pragma unroll
    for (int kc = 0; kc < 4; ++kc) {
        const int koff = kc * 64 + lg * 16;
        const int arow = wave * 16 + l15;
        const f16x8 afrag = *(const f16x8*)((char*)sX + arow * 256 + (koff ^ ((arow & 7) << 4)));
        #pragma unroll
        for (int ct = 0; ct < 8; ++ct) {
            const int col = ct * 16 + l15;
            const int sw = koff ^ ((col & 7) << 4);
            const f16x8 bfA = *(const f16x8*)((char*)sWA + col * 256 + sw);
            const f16x8 bfB = *(const f16x8*)((char*)sWB + col * 256 + sw);
            accA[ct] = __builtin_amdgcn_mfma_f32_16x16x32_f16(afrag, bfA, accA[ct], 0, 0, 0);
            accB[ct] = __builtin_amdgcn_mfma_f32_16x16x32_f16(afrag, bfB, accB[ct], 0, 0, 0);
        }
    }
    __syncthreads();   // all LDS reads done before caller restages
    #pragma unroll
    for (int q2 = 0; q2 < 4; ++q2) {
        const int gr2 = r0 + wave * 16 + lg * 4 + q2;
        if (gr2 < M) {
            #pragma unroll
            for (int ct = 0; ct < 8; ++ct) {
                const int col = ct * 16 + l15;
                Y[(size_t)gr2 * 256 + col]       = f16_of(accA[ct][q2]);
                Y[(size_t)gr2 * 256 + 128 + col] = f16_of(accB[ct][q2]);
            }
        }
    }
}

// ---------- fused scatter || projections (independent work, block-role split) ----------
// blocks [0,SC):            scatter rec -> sorted (CSR order)
// blocks [SC,SC+HB):        combo = [hidden@Wh | hidden@Ws], grid-stride tiles
// blocks [SC+HB,SC+HB+RB):  hrcombo = [rela@Wh | rela@Wr]
// block  SC+HB+RB:          qrb = rela[q_rel]@Wqr + bias
__global__ __launch_bounds__(256, 2)
void scatter_gemm(const unsigned* __restrict__ rec, const int* __restrict__ obj,
                  int* __restrict__ cursor, unsigned* __restrict__ sorted, int E,
                  const float* __restrict__ hidden, const float* __restrict__ rela,
                  const ushort_t* __restrict__ Wt4, const float* __restrict__ bias,
                  const int* __restrict__ q_rel,
                  ushort_t* __restrict__ combo, ushort_t* __restrict__ hrcombo,
                  ushort_t* __restrict__ qrb, int N, int R, int B,
                  int SC, int HB, int TB, int RB) {
    __shared__ ushort_t sWA[D * D];  // 32 KB
    __shared__ ushort_t sWB[D * D];  // 32 KB
    __shared__ ushort_t sX[64 * D];  // 16 KB
    const int t = threadIdx.x;
    const int bid = blockIdx.x;

    if (bid < SC) {   // ---- scatter role ----
        for (int e = bid * 256 + t; e < E; e += SC * 256) {
            const int pos = atomicAdd(&cursor[obj[e]], 1);
            sorted[pos] = rec[e];
        }
        return;
    }
    const int gid = bid - SC;
    const int wave = t >> 6, lane = t & 63;
    const int l15 = lane & 15, lg = lane >> 4;

    if (gid < HB) {   // ---- hidden dual projection, multiple tiles per block ----
        stage_w(sWA, Wt4 + 3 * D * D, t);       // Wh^T
        stage_w(sWB, Wt4, t);                   // Ws^T
        __syncthreads();
        for (int tile = gid; tile < TB; tile += HB)
            dual_tile(hidden, tile * 64, N, combo, sWA, sWB, sX, t);
    } else if (gid < HB + RB) {   // ---- rela dual projection ----
        stage_w(sWA, Wt4 + 3 * D * D, t);       // Wh^T
        stage_w(sWB, Wt4 + D * D, t);           // Wr^T
        __syncthreads();
        dual_tile(rela, (gid - HB) * 64, R, hrcombo, sWA, sWB, sX, t);
    } else {          // ---- qrb projection ----
        stage_w(sWA, Wt4 + 2 * D * D, t);       // Wqr^T
        __syncthreads();
        stage_x(sX, rela, q_rel, 0, B, t);
        __syncthreads();
        f32x4 acc[8];
        #pragma unroll
        for (int ct = 0; ct < 8; ++ct) acc[ct] = (f32x4){0.f, 0.f, 0.f, 0.f};
        #pragma unroll
        for (int kc = 0; kc < 4; ++kc) {
            const int koff = kc * 64 + lg * 16;
            const int arow = wave * 16 + l15;
            const f16x8 afrag = *(const f16x8*)((char*)sX + arow * 256 + (koff ^ ((arow & 7) << 4)));
            #pragma unroll
            for (int ct = 0; ct < 8; ++ct) {
                const int col = ct * 16 + l15;
                const f16x8 bf = *(const f16x8*)((char*)sWA + col * 256 + (koff ^ ((col & 7) << 4)));
                acc[ct] = __builtin_amdgcn_mfma_f32_16x16x32_f16(afrag, bf, acc[ct], 0, 0, 0);
            }
        }
        #pragma unroll
        for (int q2 = 0; q2 < 4; ++q2) {
            const int gr2 = wave * 16 + lg * 4 + q2;
            if (gr2 < B) {
                #pragma unroll
                for (int ct = 0; ct < 8; ++ct) {
                    const int col = ct * 16 + l15;
                    qrb[(size_t)gr2 * 128 + col] = f16_of(acc[ct][q2] + bias[col]);
                }
            }
        }
    }
}

// ------- per-node aggregation, fp16 packed accum: out = relu(sum a*(hw+rw)) -------
__global__ void agg_v10(const unsigned* __restrict__ sorted, const int* __restrict__ start,
                        const __half* __restrict__ combo,    // [N][256]: hw | hs_proj
                        const __half* __restrict__ hrcombo,  // [R][256]: rw | hr_proj
                        const __half* __restrict__ qrb,      // [B][128]: qr_proj
                        const float* __restrict__ Wa,
                        float* __restrict__ out, int N) {
    const int gtid = blockIdx.x * blockDim.x + threadIdx.x;
    const int wave = gtid >> 6;
    const int lane = threadIdx.x & 63;
    const int nwaves = (gridDim.x * blockDim.x) >> 6;
    const int grp = lane >> 4;        // 0..3 : edge slot within wave
    const int sl  = lane & 15;        // 0..15
    const int c   = sl * 8;           // 8 cols per lane
    __half2 wah[4];
    {
        const float4 w0 = *(const float4*)(Wa + c);
        const float4 w1 = *(const float4*)(Wa + c + 4);
        wah[0] = __floats2half2_rn(w0.x, w0.y);
        wah[1] = __floats2half2_rn(w0.z, w0.w);
        wah[2] = __floats2half2_rn(w1.x, w1.y);
        wah[3] = __floats2half2_rn(w1.z, w1.w);
    }
    const __half2 zero2 = __floats2half2_rn(0.f, 0.f);
    for (int n = wave; n < N; n += nwaves) {
        const int e0 = start[n], e1 = start[n + 1];
        __half2 a0 = zero2, a1 = zero2, a2 = zero2, a3 = zero2;
        int e = e0 + grp;
        unsigned nrec = (e < e1) ? sorted[e] : 0u;
        for (; e < e1; e += 4) {
            const unsigned rc = nrec;
            if (e + 4 < e1) nrec = sorted[e + 4];   // only the index word is prefetched
            const int sub  = rc & 0xFFFF;
            const int rel  = (rc >> 16) & 0x1FF;
            const int ridx = rc >> 25;
            const H8 uhw  = *(const H8*)(combo + (size_t)sub * 256 + c);
            const H8 uhsp = *(const H8*)(combo + (size_t)sub * 256 + 128 + c);
            const H8 urw  = *(const H8*)(hrcombo + (size_t)rel * 256 + c);
            const H8 uhrp = *(const H8*)(hrcombo + (size_t)rel * 256 + 128 + c);
            const H8 uqrp = *(const H8*)(qrb + (size_t)ridx * 128 + c);
            __half2 d2 = zero2;
            #pragma unroll
            for (int j = 0; j < 4; ++j) {
                const __half2 p = hmax2(__hadd2(__hadd2(uhsp.h[j], uhrp.h[j]), uqrp.h[j]), zero2);
                d2 = __hfma2(p, wah[j], d2);
            }
            float part = __low2float(d2) + __high2float(d2);
            #pragma unroll
            for (int off = 8; off > 0; off >>= 1) part += __shfl_xor(part, off, 64);
            const float alpha = 1.f / (1.f + __expf(-part));
            const __half2 al2 = __float2half2_rn(alpha);
            a0 = __hfma2(__hadd2(uhw.h[0], urw.h[0]), al2, a0);
            a1 = __hfma2(__hadd2(uhw.h[1], urw.h[1]), al2, a1);
            a2 = __hfma2(__hadd2(uhw.h[2], urw.h[2]), al2, a2);
            a3 = __hfma2(__hadd2(uhw.h[3], urw.h[3]), al2, a3);
        }
        __half2 aa[4] = {a0, a1, a2, a3};
        #pragma unroll
        for (int j = 0; j < 4; ++j) {   // combine the 4 edge slots
            unsigned u = __builtin_bit_cast(unsigned, aa[j]);
            __half2 s = __hadd2(aa[j], __builtin_bit_cast(__half2, __shfl_xor(u, 16, 64)));
            u = __builtin_bit_cast(unsigned, s);
            aa[j] = __hadd2(s, __builtin_bit_cast(__half2, __shfl_xor(u, 32, 64)));
        }
        if (grp == 0) {
            const float4 o0 = make_float4(fmaxf(__low2float(aa[0]), 0.f), fmaxf(__high2float(aa[0]), 0.f),
                                          fmaxf(__low2float(aa[1]), 0.f), fmaxf(__high2float(aa[1]), 0.f));
            const float4 o1 = make_float4(fmaxf(__low2float(aa[2]), 0.f), fmaxf(__high2float(aa[2]), 0.f),
                                          fmaxf(__low2float(aa[3]), 0.f), fmaxf(__high2float(aa[3]), 0.f));
            *(float4*)(out + (size_t)n * D + c)     = o0;
            *(float4*)(out + (size_t)n * D + c + 4) = o1;
        }
    }
}

extern "C" void kernel_launch(void* const* d_in, const int* in_sizes, int n_in,
                              void* d_out, int out_size, void* d_ws, size_t ws_size,
                              hipStream_t stream) {
    const int*   q_rel  = (const int*)d_in[0];
    const float* hidden = (const float*)d_in[1];
    const int*   edges  = (const int*)d_in[2];
    const float* rela   = (const float*)d_in[3];
    const float* Ws     = (const float*)d_in[4];
    const float* Wr     = (const float*)d_in[5];
    const float* Wqr_w  = (const float*)d_in[6];
    const float* Wqr_b  = (const float*)d_in[7];
    const float* Wa     = (const float*)d_in[8];
    const float* Wh     = (const float*)d_in[9];

    const int B = in_sizes[0];
    const int N = in_sizes[1] / D;
    const int E = in_sizes[2] / 6;
    const int R = in_sizes[3] / D;

    ushort_t* combo   = (ushort_t*)d_ws;                 // N*256 fp16: hw | hs_proj
    ushort_t* hrcombo = combo + (size_t)N * 256;         // R*256 fp16: rw | hr_proj
    ushort_t* qrb     = hrcombo + (size_t)R * 256;       // B*128 fp16
    ushort_t* Wt4     = qrb + (size_t)B * 128;           // 4*128*128 fp16: Ws,Wr,Wqr,Wh ^T
    int* count  = (int*)(Wt4 + 4 * D * D);               // N
    int* bsum   = count + N;                             // 64
    int* start  = bsum + 64;                             // N+1
    int* cursor = start + N + 1;                         // N
    unsigned* rec    = (unsigned*)(cursor + N);          // E
    int*      obj    = (int*)(rec + E);                  // E
    unsigned* sorted = (unsigned*)(obj + E);             // E

    // CSR build (+ fused weight transpose in blocks 0..3)
    (void)hipMemsetAsync(count, 0, (size_t)N * sizeof(int), stream);
    pack_prep<<<1028, 256, 0, stream>>>(edges, rec, obj, count, E,
                                        Ws, Wr, Wqr_w, Wh, Wt4);
    const int G = (N + 1023) / 1024;
    scan_partial<<<G, 1024, 0, stream>>>(count, bsum, N);
    scan_final<<<G, 1024, 0, stream>>>(count, bsum, start, cursor, N, G);

    // fused: scatter (atomic-bound) overlapped with all MFMA projections
    const int TB = (N + 63) / 64;
    const int RB = (R + 63) / 64;
    const int SC = 256, HB = 256;
    scatter_gemm<<<SC + HB + RB + 1, 256, 0, stream>>>(
        rec, obj, cursor, sorted, E, hidden, rela, Wt4, Wqr_b, q_rel,
        combo, hrcombo, qrb, N, R, B, SC, HB, TB, RB);

    // final: gather-aggregate + relu -> d_out
    agg_v10<<<2048, 256, 0, stream>>>(sorted, start, (const __half*)combo,
                                      (const __half*)hrcombo, (const __half*)qrb, Wa,
                                      (float*)d_out, N);
}

// Round 15
// 94.436 us; speedup vs baseline: 4.1514x; 1.2600x over previous
//
#include <hip/hip_runtime.h>
#include <hip/hip_fp16.h>
#include <math.h>
#include <stdint.h>

#define D 128
#define MAXDEG 32
typedef __attribute__((ext_vector_type(8))) _Float16 f16x8;
typedef __attribute__((ext_vector_type(4))) float f32x4;
typedef unsigned short ushort_t;

__device__ inline unsigned pack_f16(float a, float b) {
    __half2 h = __floats2half2_rn(a, b);
    return __builtin_bit_cast(unsigned, h);
}
__device__ inline ushort_t f16_of(float f) {
    __half h = __float2half_rn(f);
    return __builtin_bit_cast(ushort_t, h);
}
__device__ inline __half2 hmax2(__half2 a, __half2 b) {
    unsigned ua = __builtin_bit_cast(unsigned, a);
    unsigned ub = __builtin_bit_cast(unsigned, b);
    unsigned r;
    asm("v_pk_max_f16 %0, %1, %2" : "=v"(r) : "v"(ua), "v"(ub));
    return __builtin_bit_cast(__half2, r);
}

struct __align__(16) H8 { __half2 h[4]; };

// ---- prep: weight transpose (blocks 0..3) + zero count / ov_cnt (blocks 4+) ----
__global__ void prep(const float* __restrict__ W0, const float* __restrict__ W1,
                     const float* __restrict__ W2, const float* __restrict__ W3,
                     ushort_t* __restrict__ Wt4, int* __restrict__ count,
                     int* __restrict__ ov_cnt, int N) {
    __shared__ ushort_t sT[D * D];
    const int t = threadIdx.x;
    if (blockIdx.x < 4) {
        const float* src = blockIdx.x == 0 ? W0 : blockIdx.x == 1 ? W1 : blockIdx.x == 2 ? W2 : W3;
        ushort_t* dst = Wt4 + (size_t)blockIdx.x * (D * D);
        for (int i = t; i < D * D; i += 256) {
            const int k = i >> 7, col = i & 127;
            sT[col * D + k] = f16_of(src[i]);
        }
        __syncthreads();
        const uint4* s8 = (const uint4*)sT;
        uint4* d8 = (uint4*)dst;
        for (int i = t; i < D * D / 8; i += 256) d8[i] = s8[i];
    } else {
        if (blockIdx.x == 4 && t == 0) *ov_cnt = 0;
        for (int i = (blockIdx.x - 4) * 256 + t; i < N; i += (gridDim.x - 4) * 256)
            count[i] = 0;
    }
}

// ---- LDS staging helpers (XOR-swizzled layout, 256B rows) ----
__device__ inline void stage_w(ushort_t* sW, const ushort_t* Wt, int t) {
    const uint4* src = (const uint4*)Wt;
    for (int s = t; s < 2048; s += 256) {
        const int col = s >> 4;
        const int off = (s & 15) * 16;
        *(uint4*)((char*)sW + col * 256 + (off ^ ((col & 7) << 4))) = src[s];
    }
}
__device__ inline void stage_x(ushort_t* sX, const float* X, const int* rowidx,
                               int r0, int M, int t) {
    const int row = t >> 2, q = t & 3;
    const int gr = r0 + row;
    if (gr < M) {
        const int src = rowidx ? rowidx[gr] : gr;
        const float* xp = X + (size_t)src * D + q * 32;
        #pragma unroll
        for (int s = 0; s < 4; ++s) {
            const float4 v0 = *(const float4*)(xp + s * 8);
            const float4 v1 = *(const float4*)(xp + s * 8 + 4);
            uint4 pk;
            pk.x = pack_f16(v0.x, v0.y); pk.y = pack_f16(v0.z, v0.w);
            pk.z = pack_f16(v1.x, v1.y); pk.w = pack_f16(v1.z, v1.w);
            const int off = q * 64 + s * 16;
            *(uint4*)((char*)sX + row * 256 + (off ^ ((row & 7) << 4))) = pk;
        }
    }
}

// dual-weight 64-row tile: Y[gr][0:128]=X@(sWA), Y[gr][128:256]=X@(sWB), fp16 out
__device__ inline void dual_tile(const float* X, int r0, int M, ushort_t* Y,
                                 ushort_t* sWA, ushort_t* sWB, ushort_t* sX, int t) {
    const int wave = t >> 6, lane = t & 63;
    const int l15 = lane & 15, lg = lane >> 4;
    stage_x(sX, X, nullptr, r0, M, t);
    __syncthreads();
    f32x4 accA[8], accB[8];
    #pragma unroll
    for (int ct = 0; ct < 8; ++ct) {
        accA[ct] = (f32x4){0.f, 0.f, 0.f, 0.f};
        accB[ct] = (f32x4){0.f, 0.f, 0.f, 0.f};
    }
    #pragma unroll
    for (int kc = 0; kc < 4; ++kc) {
        const int koff = kc * 64 + lg * 16;
        const int arow = wave * 16 + l15;
        const f16x8 afrag = *(const f16x8*)((char*)sX + arow * 256 + (koff ^ ((arow & 7) << 4)));
        #pragma unroll
        for (int ct = 0; ct < 8; ++ct) {
            const int col = ct * 16 + l15;
            const int sw = koff ^ ((col & 7) << 4);
            const f16x8 bfA = *(const f16x8*)((char*)sWA + col * 256 + sw);
            const f16x8 bfB = *(const f16x8*)((char*)sWB + col * 256 + sw);
            accA[ct] = __builtin_amdgcn_mfma_f32_16x16x32_f16(afrag, bfA, accA[ct], 0, 0, 0);
            accB[ct] = __builtin_amdgcn_mfma_f32_16x16x32_f16(afrag, bfB, accB[ct], 0, 0, 0);
        }
    }
    __syncthreads();   // all LDS reads done before caller restages
    #pragma unroll
    for (int q2 = 0; q2 < 4; ++q2) {
        const int gr2 = r0 + wave * 16 + lg * 4 + q2;
        if (gr2 < M) {
            #pragma unroll
            for (int ct = 0; ct < 8; ++ct) {
                const int col = ct * 16 + l15;
                Y[(size_t)gr2 * 256 + col]       = f16_of(accA[ct][q2]);
                Y[(size_t)gr2 * 256 + 128 + col] = f16_of(accB[ct][q2]);
            }
        }
    }
}

// ---------- fused bucket-scatter || projections (block-role split) ----------
// blocks [0,SC):            read edges, bucket[obj*32+pos] = rec (overflow -> ov list)
// blocks [SC,SC+HB):        combo = [hidden@Wh | hidden@Ws], grid-stride tiles
// blocks [SC+HB,SC+HB+RB):  hrcombo = [rela@Wh | rela@Wr]
// block  SC+HB+RB:          qrb = rela[q_rel]@Wqr + bias
__global__ __launch_bounds__(256, 2)
void scatter_gemm2(const int* __restrict__ edges, int* __restrict__ count,
                   unsigned* __restrict__ bucket, uint2* __restrict__ ov,
                   int* __restrict__ ov_cnt, int E,
                   const float* __restrict__ hidden, const float* __restrict__ rela,
                   const ushort_t* __restrict__ Wt4, const float* __restrict__ bias,
                   const int* __restrict__ q_rel,
                   ushort_t* __restrict__ combo, ushort_t* __restrict__ hrcombo,
                   ushort_t* __restrict__ qrb, int N, int R, int B,
                   int SC, int HB, int TB, int RB) {
    __shared__ ushort_t sWA[D * D];  // 32 KB
    __shared__ ushort_t sWB[D * D];  // 32 KB
    __shared__ ushort_t sX[64 * D];  // 16 KB
    const int t = threadIdx.x;
    const int bid = blockIdx.x;

    if (bid < SC) {   // ---- bucket scatter role ----
        const uint2* e2 = (const uint2*)edges;
        for (int e = bid * 256 + t; e < E; e += SC * 256) {
            const unsigned r_idx = e2[e * 3 + 0].x;
            const unsigned rel   = e2[e * 3 + 1].x;
            const uint2 so       = e2[e * 3 + 2];     // .x=sub .y=obj
            const unsigned rc = so.x | (rel << 16) | (r_idx << 25);
            const int pos = atomicAdd(&count[so.y], 1);
            if (pos < MAXDEG) bucket[(size_t)so.y * MAXDEG + pos] = rc;
            else { const int i = atomicAdd(ov_cnt, 1); ov[i] = make_uint2(so.y, rc); }
        }
        return;
    }
    const int gid = bid - SC;
    const int wave = t >> 6, lane = t & 63;
    const int l15 = lane & 15, lg = lane >> 4;

    if (gid < HB) {   // ---- hidden dual projection, multiple tiles per block ----
        stage_w(sWA, Wt4 + 3 * D * D, t);       // Wh^T
        stage_w(sWB, Wt4, t);                   // Ws^T
        __syncthreads();
        for (int tile = gid; tile < TB; tile += HB)
            dual_tile(hidden, tile * 64, N, combo, sWA, sWB, sX, t);
    } else if (gid < HB + RB) {   // ---- rela dual projection ----
        stage_w(sWA, Wt4 + 3 * D * D, t);       // Wh^T
        stage_w(sWB, Wt4 + D * D, t);           // Wr^T
        __syncthreads();
        dual_tile(rela, (gid - HB) * 64, R, hrcombo, sWA, sWB, sX, t);
    } else {          // ---- qrb projection ----
        stage_w(sWA, Wt4 + 2 * D * D, t);       // Wqr^T
        __syncthreads();
        stage_x(sX, rela, q_rel, 0, B, t);
        __syncthreads();
        f32x4 acc[8];
        #pragma unroll
        for (int ct = 0; ct < 8; ++ct) acc[ct] = (f32x4){0.f, 0.f, 0.f, 0.f};
        #pragma unroll
        for (int kc = 0; kc < 4; ++kc) {
            const int koff = kc * 64 + lg * 16;
            const int arow = wave * 16 + l15;
            const f16x8 afrag = *(const f16x8*)((char*)sX + arow * 256 + (koff ^ ((arow & 7) << 4)));
            #pragma unroll
            for (int ct = 0; ct < 8; ++ct) {
                const int col = ct * 16 + l15;
                const f16x8 bf = *(const f16x8*)((char*)sWA + col * 256 + (koff ^ ((col & 7) << 4)));
                acc[ct] = __builtin_amdgcn_mfma_f32_16x16x32_f16(afrag, bf, acc[ct], 0, 0, 0);
            }
        }
        #pragma unroll
        for (int q2 = 0; q2 < 4; ++q2) {
            const int gr2 = wave * 16 + lg * 4 + q2;
            if (gr2 < B) {
                #pragma unroll
                for (int ct = 0; ct < 8; ++ct) {
                    const int col = ct * 16 + l15;
                    qrb[(size_t)gr2 * 128 + col] = f16_of(acc[ct][q2] + bias[col]);
                }
            }
        }
    }
}

// ------- per-node aggregation from buckets: out = relu(sum a*(hw+rw)) -------
__global__ void agg_v11(const unsigned* __restrict__ bucket, const int* __restrict__ count,
                        const uint2* __restrict__ ov, const int* __restrict__ ov_cnt,
                        const __half* __restrict__ combo,    // [N][256]: hw | hs_proj
                        const __half* __restrict__ hrcombo,  // [R][256]: rw | hr_proj
                        const __half* __restrict__ qrb,      // [B][128]: qr_proj
                        const float* __restrict__ Wa,
                        float* __restrict__ out, int N) {
    const int gtid = blockIdx.x * blockDim.x + threadIdx.x;
    const int wave = gtid >> 6;
    const int lane = threadIdx.x & 63;
    const int nwaves = (gridDim.x * blockDim.x) >> 6;
    const int grp = lane >> 4;        // 0..3 : edge slot within wave
    const int sl  = lane & 15;        // 0..15
    const int c   = sl * 8;           // 8 cols per lane
    __half2 wah[4];
    {
        const float4 w0 = *(const float4*)(Wa + c);
        const float4 w1 = *(const float4*)(Wa + c + 4);
        wah[0] = __floats2half2_rn(w0.x, w0.y);
        wah[1] = __floats2half2_rn(w0.z, w0.w);
        wah[2] = __floats2half2_rn(w1.x, w1.y);
        wah[3] = __floats2half2_rn(w1.z, w1.w);
    }
    const __half2 zero2 = __floats2half2_rn(0.f, 0.f);
    for (int n = wave; n < N; n += nwaves) {
        const int deg = count[n];
        const int lim = deg < MAXDEG ? deg : MAXDEG;
        __half2 a0 = zero2, a1 = zero2, a2 = zero2, a3 = zero2;
        for (int e = grp; e < lim; e += 4) {
            const unsigned rc = bucket[(size_t)n * MAXDEG + e];
            const int sub  = rc & 0xFFFF;
            const int rel  = (rc >> 16) & 0x1FF;
            const int ridx = rc >> 25;
            const H8 uhw  = *(const H8*)(combo + (size_t)sub * 256 + c);
            const H8 uhsp = *(const H8*)(combo + (size_t)sub * 256 + 128 + c);
            const H8 urw  = *(const H8*)(hrcombo + (size_t)rel * 256 + c);
            const H8 uhrp = *(const H8*)(hrcombo + (size_t)rel * 256 + 128 + c);
            const H8 uqrp = *(const H8*)(qrb + (size_t)ridx * 128 + c);
            __half2 d2 = zero2;
            #pragma unroll
            for (int j = 0; j < 4; ++j) {
                const __half2 p = hmax2(__hadd2(__hadd2(uhsp.h[j], uhrp.h[j]), uqrp.h[j]), zero2);
                d2 = __hfma2(p, wah[j], d2);
            }
            float part = __low2float(d2) + __high2float(d2);
            #pragma unroll
            for (int off = 8; off > 0; off >>= 1) part += __shfl_xor(part, off, 64);
            const float alpha = 1.f / (1.f + __expf(-part));
            const __half2 al2 = __float2half2_rn(alpha);
            a0 = __hfma2(__hadd2(uhw.h[0], urw.h[0]), al2, a0);
            a1 = __hfma2(__hadd2(uhw.h[1], urw.h[1]), al2, a1);
            a2 = __hfma2(__hadd2(uhw.h[2], urw.h[2]), al2, a2);
            a3 = __hfma2(__hadd2(uhw.h[3], urw.h[3]), al2, a3);
        }
        if (deg > MAXDEG) {   // exact-correctness overflow path (empty in practice)
            const int ovn = *ov_cnt;
            for (int i = grp; i < ovn; i += 4) {
                const uint2 o = ov[i];
                if ((int)o.x != n) continue;
                const unsigned rc = o.y;
                const int sub  = rc & 0xFFFF;
                const int rel  = (rc >> 16) & 0x1FF;
                const int ridx = rc >> 25;
                const H8 uhw  = *(const H8*)(combo + (size_t)sub * 256 + c);
                const H8 uhsp = *(const H8*)(combo + (size_t)sub * 256 + 128 + c);
                const H8 urw  = *(const H8*)(hrcombo + (size_t)rel * 256 + c);
                const H8 uhrp = *(const H8*)(hrcombo + (size_t)rel * 256 + 128 + c);
                const H8 uqrp = *(const H8*)(qrb + (size_t)ridx * 128 + c);
                __half2 d2 = zero2;
                #pragma unroll
                for (int j = 0; j < 4; ++j) {
                    const __half2 p = hmax2(__hadd2(__hadd2(uhsp.h[j], uhrp.h[j]), uqrp.h[j]), zero2);
                    d2 = __hfma2(p, wah[j], d2);
                }
                float part = __low2float(d2) + __high2float(d2);
                #pragma unroll
                for (int off = 8; off > 0; off >>= 1) part += __shfl_xor(part, off, 64);
                const float alpha = 1.f / (1.f + __expf(-part));
                const __half2 al2 = __float2half2_rn(alpha);
                a0 = __hfma2(__hadd2(uhw.h[0], urw.h[0]), al2, a0);
                a1 = __hfma2(__hadd2(uhw.h[1], urw.h[1]), al2, a1);
                a2 = __hfma2(__hadd2(uhw.h[2], urw.h[2]), al2, a2);
                a3 = __hfma2(__hadd2(uhw.h[3], urw.h[3]), al2, a3);
            }
        }
        __half2 aa[4] = {a0, a1, a2, a3};
        #pragma unroll
        for (int j = 0; j < 4; ++j) {   // combine the 4 edge slots
            unsigned u = __builtin_bit_cast(unsigned, aa[j]);
            __half2 s = __hadd2(aa[j], __builtin_bit_cast(__half2, __shfl_xor(u, 16, 64)));
            u = __builtin_bit_cast(unsigned, s);
            aa[j] = __hadd2(s, __builtin_bit_cast(__half2, __shfl_xor(u, 32, 64)));
        }
        if (grp == 0) {
            const float4 o0 = make_float4(fmaxf(__low2float(aa[0]), 0.f), fmaxf(__high2float(aa[0]), 0.f),
                                          fmaxf(__low2float(aa[1]), 0.f), fmaxf(__high2float(aa[1]), 0.f));
            const float4 o1 = make_float4(fmaxf(__low2float(aa[2]), 0.f), fmaxf(__high2float(aa[2]), 0.f),
                                          fmaxf(__low2float(aa[3]), 0.f), fmaxf(__high2float(aa[3]), 0.f));
            *(float4*)(out + (size_t)n * D + c)     = o0;
            *(float4*)(out + (size_t)n * D + c + 4) = o1;
        }
    }
}

extern "C" void kernel_launch(void* const* d_in, const int* in_sizes, int n_in,
                              void* d_out, int out_size, void* d_ws, size_t ws_size,
                              hipStream_t stream) {
    const int*   q_rel  = (const int*)d_in[0];
    const float* hidden = (const float*)d_in[1];
    const int*   edges  = (const int*)d_in[2];
    const float* rela   = (const float*)d_in[3];
    const float* Ws     = (const float*)d_in[4];
    const float* Wr     = (const float*)d_in[5];
    const float* Wqr_w  = (const float*)d_in[6];
    const float* Wqr_b  = (const float*)d_in[7];
    const float* Wa     = (const float*)d_in[8];
    const float* Wh     = (const float*)d_in[9];

    const int B = in_sizes[0];
    const int N = in_sizes[1] / D;
    const int E = in_sizes[2] / 6;
    const int R = in_sizes[3] / D;

    ushort_t* combo   = (ushort_t*)d_ws;                 // N*256 fp16: hw | hs_proj
    ushort_t* hrcombo = combo + (size_t)N * 256;         // R*256 fp16: rw | hr_proj
    ushort_t* qrb     = hrcombo + (size_t)R * 256;       // B*128 fp16
    ushort_t* Wt4     = qrb + (size_t)B * 128;           // 4*128*128 fp16
    int* count  = (int*)(Wt4 + 4 * D * D);               // N
    int* ov_cnt = count + N;                             // 1 (+pad)
    unsigned* bucket = (unsigned*)(ov_cnt + 4);          // N*MAXDEG
    uint2* ov = (uint2*)(((uintptr_t)(bucket + (size_t)N * MAXDEG) + 15) & ~(uintptr_t)15); // E

    // 1) weight transpose + zero counters
    prep<<<200, 256, 0, stream>>>(Ws, Wr, Wqr_w, Wh, Wt4, count, ov_cnt, N);

    // 2) bucket scatter || all projections
    const int TB = (N + 63) / 64;
    const int RB = (R + 63) / 64;
    const int SC = 256, HB = 256;
    scatter_gemm2<<<SC + HB + RB + 1, 256, 0, stream>>>(
        edges, count, bucket, ov, ov_cnt, E, hidden, rela, Wt4, Wqr_b, q_rel,
        combo, hrcombo, qrb, N, R, B, SC, HB, TB, RB);

    // 3) gather-aggregate + relu -> d_out
    agg_v11<<<2048, 256, 0, stream>>>(bucket, count, ov, ov_cnt,
                                      (const __half*)combo, (const __half*)hrcombo,
                                      (const __half*)qrb, Wa, (float*)d_out, N);
}